// Round 11
// baseline (8950.439 us; speedup 1.0000x reference)
//
#include <hip/hip_runtime.h>

#define T_STEPS 8192
#define BATCH   128
#define HID     128
#define NTHR    512               // 8 waves, 2/SIMD
#define NBLK    (BATCH / 2)       // 2 chains per block

typedef float v2f __attribute__((ext_vector_type(2)));

// tanh(z) = sign(z) * (1 - e^{-2|z|}) / (1 + e^{-2|z|})  -- no overflow path
__device__ __forceinline__ float fast_tanh(float z) {
    float az = fabsf(z);
    float e  = __expf(-2.0f * az);
    float r  = __fdividef(1.0f - e, 1.0f + e);
    return copysignf(r, z);
}

// wave64 sum via DPP (VALU-only, 6 dependent adds), broadcast from lane 63.
__device__ __forceinline__ float wave64_sum(float x) {
#define DPP_ADD(ctrl) do {                                                        \
        int t_ = __builtin_amdgcn_update_dpp(0, __builtin_bit_cast(int, x),       \
                                             (ctrl), 0xf, 0xf, false);            \
        x += __builtin_bit_cast(float, t_); } while (0)
    DPP_ADD(0x111); DPP_ADD(0x112); DPP_ADD(0x114);
    DPP_ADD(0x118); DPP_ADD(0x142); DPP_ADD(0x143);
#undef DPP_ADD
    int s_ = __builtin_amdgcn_readlane(__builtin_bit_cast(int, x), 63);
    return __builtin_bit_cast(float, s_);
}

__device__ __forceinline__ float bcast_lane(float v, int l) {
    int r = __builtin_amdgcn_readlane(__builtin_bit_cast(int, v), l);
    return __builtin_bit_cast(float, r);
}

#define FORALL16(M) M(0) M(1) M(2) M(3) M(4) M(5) M(6) M(7) \
                    M(8) M(9) M(10) M(11) M(12) M(13) M(14) M(15)

// R11: TWO independent batch chains per block. R8/R9/R10 proved the step is
// latency-bound at ~1400 cyc with barrier-lockstep waves whose stalls are
// perfectly correlated (co-resident waves stall on the same LDS ops at the
// same time -- they hide nothing). The only uncorrelated work available is
// another chain: interleaving chains 2bx and 2bx+1 in one instruction stream
// converts TLP->ILP (chain B's FMAs fill chain A's lgkmcnt waits; two DPP
// reduction trees overlap). Weight registers are SHARED between chains.
__global__ __launch_bounds__(NTHR, 2) void odenet_scan(
    const float* __restrict__ x,
    const float* __restrict__ W1, const float* __restrict__ b1,
    const float* __restrict__ W2, const float* __restrict__ b2,
    const float* __restrict__ W3, const float* __restrict__ b3,
    float* __restrict__ out) {

    const int b0   = 2 * blockIdx.x;        // chain 0
    const int b1_  = 2 * blockIdx.x + 1;    // chain 1
    const int tid  = threadIdx.x;
    const int w    = tid >> 6;              // wave 0..7
    const int s    = tid >> 7;              // k-split 0..3 (uniform per wave-pair)
    const int j    = tid & (HID - 1);       // output hidden unit 0..127
    const int lane = tid & 63;
    const int k1   = (s << 5) | (lane & 31);   // h1 unit this lane computes

    __shared__ __align__(16) float h1w[8][64];        // [wave][chain*32 + k]
    __shared__ __align__(16) float pbuf[2][2][4 * HID]; // [parity][chain][j*4+perm]

    // ---- W2 fragment: rows [32s, 32s+32) of column j, packed as 16 v2f ----
    // shared by both chains -- no extra register cost for chain 2
    const float* col = W2 + j;              // column j, row stride HID
    const int kb = s << 5;
#define DECLW(i) v2f wp##i = {col[(kb + 2*(i) + 0) * HID],                        \
                              col[(kb + 2*(i) + 1) * HID]};
    FORALL16(DECLW)
#undef DECLW
#define PINW(i) asm volatile("" : "+v"(wp##i));
    FORALL16(PINW)
#undef PINW

    float w1xk = W1[k1], w1yk = W1[HID + k1], b1k = b1[k1];
    float b2a = b2[lane], b2b = b2[lane + 64];
    float w3a = W3[lane], w3b = W3[lane + 64];
    float b3v = b3[0];
    asm volatile("" : "+v"(w1xk), "+v"(w1yk), "+v"(b1k), "+v"(b2a), "+v"(b2b),
                      "+v"(w3a), "+v"(w3b), "+v"(b3v));

    const int pstore = (j << 2) | ((s + (j >> 3)) & 3);  // rotated transpose
    const float4* h4c0 = (const float4*)&h1w[w][0];
    const float4* h4c1 = (const float4*)&h1w[w][32];

    float y0 = 0.0f, y1 = 0.0f;
    float xbuf0 = 0.0f, xbuf1 = 0.0f;  // per wave: lane l holds x[(tblk+l)*B+b]
    float ybuf = 0.0f;                 // wave 0 -> chain0 states, wave 1 -> chain1
    if (w == 0 && lane == 0) out[b0] = 0.0f;   // y_0 = 0
    if (w == 1 && lane == 0) out[b1_] = 0.0f;

    for (int t = 0; t < T_STEPS - 1; ++t) {
        const int tm = t & 63;
        if (tm == 0) {                              // one x block per 64 steps
            xbuf0 = x[(t + lane) * BATCH + b0];
            xbuf1 = x[(t + lane) * BATCH + b1_];
        }
        float xv0 = bcast_lane(xbuf0, tm);          // uniform (SGPR)
        float xv1 = bcast_lane(xbuf1, tm);

        // ---- layer 1, both chains -> own wave's LDS region (lgkmcnt only) ----
        h1w[w][(lane & 31)]      = fast_tanh(fmaf(xv0, w1xk, fmaf(y0, w1yk, b1k)));
        h1w[w][32 + (lane & 31)] = fast_tanh(fmaf(xv1, w1xk, fmaf(y1, w1yk, b1k)));

        // ---- layer 2 partials: 16 broadcast b128 reads + 32 pk_fma (2 chains,
        // independent dataflow -> compiler interleaves, stalls uncorrelated) ----
        v2f a00 = {0.f,0.f}, a01 = {0.f,0.f}, a02 = {0.f,0.f}, a03 = {0.f,0.f};
        v2f a10 = {0.f,0.f}, a11 = {0.f,0.f}, a12 = {0.f,0.f}, a13 = {0.f,0.f};
        {
            float4 q0 = h4c0[0], q1 = h4c0[1], q2 = h4c0[2], q3 = h4c0[3];
            float4 q4 = h4c0[4], q5 = h4c0[5], q6 = h4c0[6], q7 = h4c0[7];
            float4 r0 = h4c1[0], r1 = h4c1[1], r2 = h4c1[2], r3 = h4c1[3];
            float4 r4 = h4c1[4], r5 = h4c1[5], r6 = h4c1[6], r7 = h4c1[7];
#define ACC(A0,A1,A2,A3, Q0,Q1,Q2,Q3,Q4,Q5,Q6,Q7)                                 \
            { v2f h0={Q0.x,Q0.y},h1_={Q0.z,Q0.w},h2={Q1.x,Q1.y},h3={Q1.z,Q1.w};   \
              v2f h4v={Q2.x,Q2.y},h5={Q2.z,Q2.w},h6={Q3.x,Q3.y},h7={Q3.z,Q3.w};   \
              v2f h8={Q4.x,Q4.y},h9={Q4.z,Q4.w},hA={Q5.x,Q5.y},hB={Q5.z,Q5.w};    \
              v2f hC={Q6.x,Q6.y},hD={Q6.z,Q6.w},hE={Q7.x,Q7.y},hF={Q7.z,Q7.w};    \
              A0 += wp0*h0;  A1 += wp1*h1_; A2 += wp2*h2;  A3 += wp3*h3;          \
              A0 += wp4*h4v; A1 += wp5*h5;  A2 += wp6*h6;  A3 += wp7*h7;          \
              A0 += wp8*h8;  A1 += wp9*h9;  A2 += wp10*hA; A3 += wp11*hB;         \
              A0 += wp12*hC; A1 += wp13*hD; A2 += wp14*hE; A3 += wp15*hF; }
            ACC(a00,a01,a02,a03, q0,q1,q2,q3,q4,q5,q6,q7)
            ACC(a10,a11,a12,a13, r0,r1,r2,r3,r4,r5,r6,r7)
#undef ACC
        }
        v2f ap0 = (a00 + a01) + (a02 + a03);
        v2f ap1 = (a10 + a11) + (a12 + a13);
        pbuf[t & 1][0][pstore] = ap0.x + ap0.y;
        pbuf[t & 1][1][pstore] = ap1.x + ap1.y;

        __syncthreads();   // the ONLY barrier

        // ---- phase C, both chains, redundant in all waves (bit-identical) ----
        const float4* pc0 = (const float4*)pbuf[t & 1][0];
        const float4* pc1 = (const float4*)pbuf[t & 1][1];
        float4 qa0 = pc0[lane], qb0 = pc0[lane + 64];
        float4 qa1 = pc1[lane], qb1 = pc1[lane + 64];
        float sa0 = (qa0.x + qa0.y) + (qa0.z + qa0.w);
        float sb0 = (qb0.x + qb0.y) + (qb0.z + qb0.w);
        float sa1 = (qa1.x + qa1.y) + (qa1.z + qa1.w);
        float sb1 = (qb1.x + qb1.y) + (qb1.z + qb1.w);
        float c0 = fmaf(w3a, fast_tanh(sa0 + b2a), w3b * fast_tanh(sb0 + b2b));
        float c1 = fmaf(w3a, fast_tanh(sa1 + b2a), w3b * fast_tanh(sb1 + b2b));
        y0 += wave64_sum(c0) + b3v;                 // DT = 1.0
        y1 += wave64_sum(c1) + b3v;                 // two DPP trees overlap

        // capture + batched store: wave 0 -> chain 0, wave 1 -> chain 1
        if (w == 0) {
            ybuf = (lane == tm) ? y0 : ybuf;
            if (tm == 63) out[(t - 62 + lane) * BATCH + b0] = ybuf;
        } else if (w == 1) {
            ybuf = (lane == tm) ? y1 : ybuf;
            if (tm == 63) out[(t - 62 + lane) * BATCH + b1_] = ybuf;
        }
    }
    // tail: t=8128..8190 captured y_8129..y_8191 in lanes 0..62
    if (w == 0 && lane < 63) out[(T_STEPS - 63 + lane) * BATCH + b0]  = ybuf;
    if (w == 1 && lane < 63) out[(T_STEPS - 63 + lane) * BATCH + b1_] = ybuf;
}

extern "C" void kernel_launch(void* const* d_in, const int* in_sizes, int n_in,
                              void* d_out, int out_size, void* d_ws, size_t ws_size,
                              hipStream_t stream) {
    const float* x  = (const float*)d_in[0];
    const float* W1 = (const float*)d_in[1];
    const float* b1 = (const float*)d_in[2];
    const float* W2 = (const float*)d_in[3];
    const float* b2 = (const float*)d_in[4];
    const float* W3 = (const float*)d_in[5];
    const float* b3 = (const float*)d_in[6];

    odenet_scan<<<dim3(NBLK), dim3(NTHR), 0, stream>>>(
        x, W1, b1, W2, b2, W3, b3, (float*)d_out);
}

// Round 12
// 7810.921 us; speedup vs baseline: 1.1459x; 1.1459x over previous
//
#include <hip/hip_runtime.h>

#define T_STEPS 8192
#define BATCH   128
#define HID     128
#define NTHR    128               // 2 waves; wave w owns units [64w, 64w+64)
#define NREP    8                 // replica blocks per chain (co-residency)

typedef float v2f __attribute__((ext_vector_type(2)));

// tanh(z) = sign(z) * (1 - e^{-2|z|}) / (1 + e^{-2|z|})  -- no overflow path
__device__ __forceinline__ float fast_tanh(float z) {
    float az = fabsf(z);
    float e  = __expf(-2.0f * az);
    float r  = __fdividef(1.0f - e, 1.0f + e);
    return copysignf(r, z);
}

// wave64 sum via DPP (VALU-only, 6 dependent adds), broadcast from lane 63.
__device__ __forceinline__ float wave64_sum(float x) {
#define DPP_ADD(ctrl) do {                                                        \
        int t_ = __builtin_amdgcn_update_dpp(0, __builtin_bit_cast(int, x),       \
                                             (ctrl), 0xf, 0xf, false);            \
        x += __builtin_bit_cast(float, t_); } while (0)
    DPP_ADD(0x111); DPP_ADD(0x112); DPP_ADD(0x114);
    DPP_ADD(0x118); DPP_ADD(0x142); DPP_ADD(0x143);
#undef DPP_ADD
    int s_ = __builtin_amdgcn_readlane(__builtin_bit_cast(int, x), 63);
    return __builtin_bit_cast(float, s_);
}

__device__ __forceinline__ float bcast_lane(float v, int l) {
    int r = __builtin_amdgcn_readlane(__builtin_bit_cast(int, v), l);
    return __builtin_bit_cast(float, r);
}

#define FORALL64(M) M(0) M(1) M(2) M(3) M(4) M(5) M(6) M(7) M(8) M(9) \
    M(10) M(11) M(12) M(13) M(14) M(15) M(16) M(17) M(18) M(19) \
    M(20) M(21) M(22) M(23) M(24) M(25) M(26) M(27) M(28) M(29) \
    M(30) M(31) M(32) M(33) M(34) M(35) M(36) M(37) M(38) M(39) \
    M(40) M(41) M(42) M(43) M(44) M(45) M(46) M(47) M(48) M(49) \
    M(50) M(51) M(52) M(53) M(54) M(55) M(56) M(57) M(58) M(59) \
    M(60) M(61) M(62) M(63)

// R12: the minimum structure the fp32 register-wall invariant allows.
// 2 waves, UNIT-split (lane l of wave w owns unit 64w+l, FULL K=128):
//  - h1 computed redundantly IN-WAVE (2 tanh/lane) -> RT#1 never crosses waves
//  - cross-wave exchange = ONE SCALAR per wave (post-DPP dy partial): minimal
//    pre-barrier drain, 2-wave barrier (smallest arrival spread possible)
//  - tanh(h2) sits BEFORE the exchange; after the barrier: read2 + add only
// Grid NREP-replicated for 2-waves/SIMD co-residency without widening the
// barrier; only blocks < BATCH store.
__global__ __launch_bounds__(NTHR, 2) void odenet_scan(
    const float* __restrict__ x,
    const float* __restrict__ W1, const float* __restrict__ b1,
    const float* __restrict__ W2, const float* __restrict__ b2,
    const float* __restrict__ W3, const float* __restrict__ b3,
    float* __restrict__ out) {

    const int bx    = blockIdx.x;
    const int chain = bx & (BATCH - 1);     // batch element
    const bool primary = bx < BATCH;        // only primaries store
    const int tid  = threadIdx.x;
    const int w    = tid >> 6;              // wave 0..1
    const int lane = tid & 63;
    const int u    = (w << 6) | lane;       // owned hidden unit, full K

    __shared__ __align__(16) float h1w[2][HID];  // wave-private h1 copies
    __shared__ float dyx[2][2];                  // [parity][wave] dy partials

    // ---- W2 column u, all 128 K, packed as 64 v2f (128 regs; AGPR-resident
    // per R9 precedent at 64 regs -- this is the 2x probe of that cap) ----
    const float* col = W2 + u;              // row stride HID
#define DECLW(i) v2f wp##i = {col[(2*(i) + 0) * HID], col[(2*(i) + 1) * HID]};
    FORALL64(DECLW)
#undef DECLW
#define PINW(i) asm volatile("" : "+v"(wp##i));
    FORALL64(PINW)
#undef PINW

    // layer-1 weights for h1[lane] and h1[lane+64] (computed in-wave)
    float w1xa = W1[lane],      w1ya = W1[HID + lane],      b1a = b1[lane];
    float w1xb = W1[lane + 64], w1yb = W1[HID + lane + 64], b1b = b1[lane + 64];
    float b2u = b2[u], w3u = W3[u], b3v = b3[0];
    asm volatile("" : "+v"(w1xa), "+v"(w1ya), "+v"(b1a),
                      "+v"(w1xb), "+v"(w1yb), "+v"(b1b),
                      "+v"(b2u), "+v"(w3u), "+v"(b3v));

    float y    = 0.0f;
    float xbuf = 0.0f;   // per wave: lane l holds x[(tblk+l)*B + chain]
    float ybuf = 0.0f;   // primary wave 0: lane l holds y_{tblk+l+1}
    if (primary && tid == 0) out[chain] = 0.0f;   // y_0 = 0

    const float4* h4 = (const float4*)h1w[w];

    for (int t = 0; t < T_STEPS - 1; ++t) {
        const int tm = t & 63;
        if (tm == 0)                                // one x block per 64 steps
            xbuf = x[(t + lane) * BATCH + chain];
        float xv = bcast_lane(xbuf, tm);            // uniform (SGPR)

        // ---- layer 1: this wave computes ALL 128 h1 (2/lane) -> own region.
        // Same-wave RAW only -> lgkmcnt, NO barrier.
        h1w[w][lane]      = fast_tanh(fmaf(y, w1ya, fmaf(xv, w1xa, b1a)));
        h1w[w][lane + 64] = fast_tanh(fmaf(y, w1yb, fmaf(xv, w1xb, b1b)));

        // ---- layer 2: full-K dot for unit u: 32 broadcast b128 + 64 pk_fma
        v2f a0 = {0.f, 0.f}, a1 = {0.f, 0.f}, a2 = {0.f, 0.f}, a3 = {0.f, 0.f};
#define D(j, A, B, WA, WB) { float4 q = h4[j];                                    \
        v2f lo = {q.x, q.y}, hi = {q.z, q.w};                                     \
        A += WA * lo; B += WB * hi; }
        D( 0,a0,a1,wp0 ,wp1 ) D( 1,a2,a3,wp2 ,wp3 ) D( 2,a0,a1,wp4 ,wp5 )
        D( 3,a2,a3,wp6 ,wp7 ) D( 4,a0,a1,wp8 ,wp9 ) D( 5,a2,a3,wp10,wp11)
        D( 6,a0,a1,wp12,wp13) D( 7,a2,a3,wp14,wp15) D( 8,a0,a1,wp16,wp17)
        D( 9,a2,a3,wp18,wp19) D(10,a0,a1,wp20,wp21) D(11,a2,a3,wp22,wp23)
        D(12,a0,a1,wp24,wp25) D(13,a2,a3,wp26,wp27) D(14,a0,a1,wp28,wp29)
        D(15,a2,a3,wp30,wp31) D(16,a0,a1,wp32,wp33) D(17,a2,a3,wp34,wp35)
        D(18,a0,a1,wp36,wp37) D(19,a2,a3,wp38,wp39) D(20,a0,a1,wp40,wp41)
        D(21,a2,a3,wp42,wp43) D(22,a0,a1,wp44,wp45) D(23,a2,a3,wp46,wp47)
        D(24,a0,a1,wp48,wp49) D(25,a2,a3,wp50,wp51) D(26,a0,a1,wp52,wp53)
        D(27,a2,a3,wp54,wp55) D(28,a0,a1,wp56,wp57) D(29,a2,a3,wp58,wp59)
        D(30,a0,a1,wp60,wp61) D(31,a2,a3,wp62,wp63)
#undef D
        v2f ap = (a0 + a1) + (a2 + a3);

        // ---- layer 2 tanh + layer 3 partial + in-wave reduce (pre-exchange)
        float h2 = fast_tanh((ap.x + ap.y) + b2u);
        float dyw = wave64_sum(w3u * h2);           // units [64w,64w+64)

        // ---- cross-wave exchange: ONE scalar per wave, 2-wave barrier ----
        if (lane == 0) dyx[t & 1][w] = dyw;
        __syncthreads();                            // minimal drain: 1 b32 write
        y += (dyx[t & 1][0] + dyx[t & 1][1]) + b3v; // DT = 1.0; identical both waves

        // capture + batched store (primary block, wave 0)
        if (primary && tid < 64) {
            ybuf = (lane == tm) ? y : ybuf;
            if (tm == 63)
                out[(t - 62 + lane) * BATCH + chain] = ybuf;
        }
    }
    // tail: t=8128..8190 captured y_8129..y_8191 in lanes 0..62
    if (primary && tid < 63)
        out[(T_STEPS - 63 + lane) * BATCH + chain] = ybuf;
}

extern "C" void kernel_launch(void* const* d_in, const int* in_sizes, int n_in,
                              void* d_out, int out_size, void* d_ws, size_t ws_size,
                              hipStream_t stream) {
    const float* x  = (const float*)d_in[0];
    const float* W1 = (const float*)d_in[1];
    const float* b1 = (const float*)d_in[2];
    const float* W2 = (const float*)d_in[3];
    const float* b2 = (const float*)d_in[4];
    const float* W3 = (const float*)d_in[5];
    const float* b3 = (const float*)d_in[6];

    odenet_scan<<<dim3(BATCH * NREP), dim3(NTHR), 0, stream>>>(
        x, W1, b1, W2, b2, W3, b3, (float*)d_out);
}

// Round 13
// 7277.829 us; speedup vs baseline: 1.2298x; 1.0732x over previous
//
#include <hip/hip_runtime.h>

#define T_STEPS 8192
#define BATCH   128
#define HID     128
#define NTHR    512               // 8 waves, 2/SIMD (R8-proven latency hiding)
#define NREP    4                 // replica blocks per chain (DVFS ballast)

typedef float v2f __attribute__((ext_vector_type(2)));

// tanh(z) = sign(z) * (1 - e^{-2|z|}) / (1 + e^{-2|z|})  -- no overflow path
__device__ __forceinline__ float fast_tanh(float z) {
    float az = fabsf(z);
    float e  = __expf(-2.0f * az);
    float r  = __fdividef(1.0f - e, 1.0f + e);
    return copysignf(r, z);
}

// wave64 sum via DPP (VALU-only, 6 dependent adds), broadcast from lane 63.
__device__ __forceinline__ float wave64_sum(float x) {
#define DPP_ADD(ctrl) do {                                                        \
        int t_ = __builtin_amdgcn_update_dpp(0, __builtin_bit_cast(int, x),       \
                                             (ctrl), 0xf, 0xf, false);            \
        x += __builtin_bit_cast(float, t_); } while (0)
    DPP_ADD(0x111); DPP_ADD(0x112); DPP_ADD(0x114);
    DPP_ADD(0x118); DPP_ADD(0x142); DPP_ADD(0x143);
#undef DPP_ADD
    int s_ = __builtin_amdgcn_readlane(__builtin_bit_cast(int, x), 63);
    return __builtin_bit_cast(float, s_);
}

__device__ __forceinline__ float bcast_lane(float v, int l) {
    int r = __builtin_amdgcn_readlane(__builtin_bit_cast(int, v), l);
    return __builtin_bit_cast(float, r);
}

#define FORALL16(M) M(0) M(1) M(2) M(3) M(4) M(5) M(6) M(7) \
                    M(8) M(9) M(10) M(11) M(12) M(13) M(14) M(15)

// R13 = R10 byte-identical structure + NREP replica blocks per chain.
// CONTROLLED EXPERIMENT: 12 rounds of structural variation left dur pinned
// at ~1400 nominal cyc/step while every latency model says ~700-900. The
// constant ~1.7x multiplier points at sub-boost DVFS on a ~95%-idle chip,
// not at the kernel. Replicas are independent blocks doing identical chain
// work (no stores) -- the barrier stays 8-wave, the chain untouched; only
// chip utilization (and hence the clock governor's input) changes.
__global__ __launch_bounds__(NTHR, 2) void odenet_scan(
    const float* __restrict__ x,
    const float* __restrict__ W1, const float* __restrict__ b1,
    const float* __restrict__ W2, const float* __restrict__ b2,
    const float* __restrict__ W3, const float* __restrict__ b3,
    float* __restrict__ out) {

    const int b    = blockIdx.x & (BATCH - 1);   // chain this block computes
    const bool primary = blockIdx.x < BATCH;     // only primaries store
    const int tid  = threadIdx.x;
    const int w    = tid >> 6;          // wave 0..7
    const int s    = tid >> 7;          // k-split 0..3 (uniform per wave-pair)
    const int j    = tid & (HID - 1);   // output hidden unit 0..127
    const int lane = tid & 63;
    const int k1   = (s << 5) | (lane & 31);   // h1 unit this lane computes

    __shared__ __align__(16) float h1w[8][32];        // wave-private h1 copies
    __shared__ __align__(16) float pbuf[2][4 * HID];  // [parity][j*4 + perm]

    // ---- W2 fragment: rows [32s, 32s+32) of column j, packed as 16 v2f ----
    const float* col = W2 + j;          // column j, row stride HID
    const int kb = s << 5;
#define DECLW(i) v2f wp##i = {col[(kb + 2*(i) + 0) * HID],                        \
                              col[(kb + 2*(i) + 1) * HID]};
    FORALL16(DECLW)
#undef DECLW
#define PINW(i) asm volatile("" : "+v"(wp##i));
    FORALL16(PINW)
#undef PINW

    float w1xk = W1[k1], w1yk = W1[HID + k1], b1k = b1[k1];
    float b2a = b2[lane], b2b = b2[lane + 64];
    float w3a = W3[lane], w3b = W3[lane + 64];
    float b3v = b3[0];
    asm volatile("" : "+v"(w1xk), "+v"(w1yk), "+v"(b1k), "+v"(b2a), "+v"(b2b),
                      "+v"(w3a), "+v"(w3b), "+v"(b3v));

    const int pstore = (j << 2) | ((s + (j >> 3)) & 3);  // rotated transpose
    const float4* h4 = (const float4*)h1w[w];

    float y    = 0.0f;
    float xbuf = 0.0f;   // per wave: lane l holds x[(tblk+l)*B + b]
    float ybuf = 0.0f;   // wave 0: lane l holds y_{tblk+l+1}
    if (primary && tid == 0) out[b] = 0.0f;      // y_0 = 0

    for (int t = 0; t < T_STEPS - 1; ++t) {
        const int tm = t & 63;
        if (tm == 0)                                // one x block per 64 steps
            xbuf = x[(t + lane) * BATCH + b];       // same addrs all waves (L1)
        float xv = bcast_lane(xbuf, tm);            // uniform (SGPR)

        // ---- layer 1: lane computes h1[k1] -> OWN wave's LDS region.
        // Lanes l and l+32 write the same addr with the same value (benign).
        // Same-wave RAW only -> lgkmcnt, NO barrier.
        h1w[w][lane & 31] = fast_tanh(fmaf(xv, w1xk, fmaf(y, w1yk, b1k)));

        // ---- layer 2 partial: 8 broadcast b128 reads + 16 v_pk_fma_f32 ----
        v2f acc0 = {0.f, 0.f}, acc1 = {0.f, 0.f};
        v2f acc2 = {0.f, 0.f}, acc3 = {0.f, 0.f};
        {
            float4 q0 = h4[0], q1 = h4[1], q2 = h4[2], q3 = h4[3];
            float4 q4 = h4[4], q5 = h4[5], q6 = h4[6], q7 = h4[7];
            v2f h0 = {q0.x, q0.y}, h1_ = {q0.z, q0.w};
            v2f h2 = {q1.x, q1.y}, h3 = {q1.z, q1.w};
            v2f h4v = {q2.x, q2.y}, h5 = {q2.z, q2.w};
            v2f h6 = {q3.x, q3.y}, h7 = {q3.z, q3.w};
            v2f h8 = {q4.x, q4.y}, h9 = {q4.z, q4.w};
            v2f h10 = {q5.x, q5.y}, h11 = {q5.z, q5.w};
            v2f h12 = {q6.x, q6.y}, h13 = {q6.z, q6.w};
            v2f h14 = {q7.x, q7.y}, h15 = {q7.z, q7.w};
            acc0 += wp0 * h0;   acc1 += wp1 * h1_;
            acc2 += wp2 * h2;   acc3 += wp3 * h3;
            acc0 += wp4 * h4v;  acc1 += wp5 * h5;
            acc2 += wp6 * h6;   acc3 += wp7 * h7;
            acc0 += wp8 * h8;   acc1 += wp9 * h9;
            acc2 += wp10 * h10; acc3 += wp11 * h11;
            acc0 += wp12 * h12; acc1 += wp13 * h13;
            acc2 += wp14 * h14; acc3 += wp15 * h15;
        }
        v2f accp = (acc0 + acc1) + (acc2 + acc3);
        pbuf[t & 1][pstore] = accp.x + accp.y;

        __syncthreads();   // the ONLY barrier: cross-wave partials visible

        // ---- phase C, redundant in all 8 waves (bit-identical) ----
        const float4* pb4 = (const float4*)pbuf[t & 1];
        float4 qa = pb4[lane];        // 4 partials of unit lane (permuted)
        float4 qb = pb4[lane + 64];   // 4 partials of unit lane+64
        float sa = (qa.x + qa.y) + (qa.z + qa.w);
        float sb = (qb.x + qb.y) + (qb.z + qb.w);
        float c = fmaf(w3a, fast_tanh(sa + b2a), w3b * fast_tanh(sb + b2b));
        y += wave64_sum(c) + b3v;                    // DT = 1.0

        // capture + batched store (primary block, wave 0 only)
        if (primary && tid < 64) {
            ybuf = (lane == tm) ? y : ybuf;
            if (tm == 63)
                out[(t - 62 + lane) * BATCH + b] = ybuf;
        }
    }
    // tail: t=8128..8190 captured y_8129..y_8191 in lanes 0..62 of wave 0
    if (primary && tid < 63)
        out[(T_STEPS - 63 + lane) * BATCH + b] = ybuf;
}

extern "C" void kernel_launch(void* const* d_in, const int* in_sizes, int n_in,
                              void* d_out, int out_size, void* d_ws, size_t ws_size,
                              hipStream_t stream) {
    const float* x  = (const float*)d_in[0];
    const float* W1 = (const float*)d_in[1];
    const float* b1 = (const float*)d_in[2];
    const float* W2 = (const float*)d_in[3];
    const float* b2 = (const float*)d_in[4];
    const float* W3 = (const float*)d_in[5];
    const float* b3 = (const float*)d_in[6];

    odenet_scan<<<dim3(BATCH * NREP), dim3(NTHR), 0, stream>>>(
        x, W1, b1, W2, b2, W3, b3, (float*)d_out);
}

// Round 14
// 4021.575 us; speedup vs baseline: 2.2256x; 1.8097x over previous
//
#include <hip/hip_runtime.h>

#define T_STEPS 8192
#define BATCH   128
#define HID     128
#define NTHR    512               // 8 waves, 2/SIMD, 1 block/CU

typedef float v2f __attribute__((ext_vector_type(2)));

// tanh(z) = 1 - 2/(1+e^{2z}) -- 5 instrs, NaN-free at both infinities:
// z>>0: e=inf -> rcp(inf)=0 -> 1;  z<<0: e=0 -> rcp(1)=1 -> -1.
__device__ __forceinline__ float fast_tanh(float z) {
    float e = __expf(2.0f * z);
    float r = __builtin_amdgcn_rcpf(1.0f + e);
    return fmaf(-2.0f, r, 1.0f);
}

// sum over the 4 lanes of a quad via 2 quad_perm DPP adds; all 4 lanes get
// the bitwise-identical result ((a0+a1)+(a2+a3), fp-add commutativity).
__device__ __forceinline__ float quad_sum(float x) {
    int t1 = __builtin_amdgcn_update_dpp(0, __builtin_bit_cast(int, x),
                                         0xB1 /*[1,0,3,2]*/, 0xf, 0xf, false);
    x += __builtin_bit_cast(float, t1);
    int t2 = __builtin_amdgcn_update_dpp(0, __builtin_bit_cast(int, x),
                                         0x4E /*[2,3,0,1]*/, 0xf, 0xf, false);
    x += __builtin_bit_cast(float, t2);
    return x;
}

// wave64 sum via DPP (6 dependent adds), broadcast from lane 63.
__device__ __forceinline__ float wave64_sum(float x) {
#define DPP_ADD(ctrl) do {                                                        \
        int t_ = __builtin_amdgcn_update_dpp(0, __builtin_bit_cast(int, x),       \
                                             (ctrl), 0xf, 0xf, false);            \
        x += __builtin_bit_cast(float, t_); } while (0)
    DPP_ADD(0x111); DPP_ADD(0x112); DPP_ADD(0x114);
    DPP_ADD(0x118); DPP_ADD(0x142); DPP_ADD(0x143);
#undef DPP_ADD
    int s_ = __builtin_amdgcn_readlane(__builtin_bit_cast(int, x), 63);
    return __builtin_bit_cast(float, s_);
}

__device__ __forceinline__ float bcast_lane(float v, int l) {
    int r = __builtin_amdgcn_readlane(__builtin_bit_cast(int, v), l);
    return __builtin_bit_cast(float, r);
}

#define FORALL16(M) M(0) M(1) M(2) M(3) M(4) M(5) M(6) M(7) \
                    M(8) M(9) M(10) M(11) M(12) M(13) M(14) M(15)

// R14: quad-local k-split -- the pbuf LDS round-trip (write partials ->
// barrier -> b128 read, ~250+ cyc of R10's chain) is replaced by 2 quad_perm
// DPP adds (~16 cyc). Lane l: j = 16w + (l>>2), k-chunk s = l&3. The only
// cross-wave traffic left is ONE scalar per wave (post-DPP dy partial).
// R13 proved ballast backfires (clock governor); grid stays 128, 1 block/CU.
__global__ __launch_bounds__(NTHR, 2) void odenet_scan(
    const float* __restrict__ x,
    const float* __restrict__ W1, const float* __restrict__ b1,
    const float* __restrict__ W2, const float* __restrict__ b2,
    const float* __restrict__ W3, const float* __restrict__ b3,
    float* __restrict__ out) {

    const int b    = blockIdx.x;        // batch element
    const int tid  = threadIdx.x;
    const int w    = tid >> 6;          // wave 0..7
    const int lane = tid & 63;
    const int j    = (w << 4) | (lane >> 2);   // owned output unit
    const int s    = lane & 3;                 // k-chunk [32s, 32s+32)

    // wave-private h1: 4 chunks x 36 floats (32 + 4 pad) -> b128 reads of the
    // 4 chunks hit disjoint bank quads {0-3}{4-7}{8-11}{12-15}; writes 2-way.
    __shared__ __align__(16) float h1buf[8][144];
    __shared__ __align__(16) float dyx[2][8];  // [parity][wave] dy partials

    // ---- W2 fragment: rows [32s, 32s+32) of column j, packed as 16 v2f ----
    const float* col = W2 + j;          // column j, row stride HID
    const int kb = s << 5;
#define DECLW(i) v2f wp##i = {col[(kb + 2*(i) + 0) * HID],                        \
                              col[(kb + 2*(i) + 1) * HID]};
    FORALL16(DECLW)
#undef DECLW
#define PINW(i) asm volatile("" : "+v"(wp##i));
    FORALL16(PINW)
#undef PINW

    // layer-1 weights for the two h1 units this lane computes (k=lane, lane+64)
    float w1xa = W1[lane],      w1ya = W1[HID + lane],      b1a = b1[lane];
    float w1xb = W1[lane + 64], w1yb = W1[HID + lane + 64], b1b = b1[lane + 64];
    float b2j  = b2[j];
    float w3j4 = W3[j] * 0.25f;         // /4: each j appears in 4 quad lanes
    float b3v  = b3[0];
    asm volatile("" : "+v"(w1xa), "+v"(w1ya), "+v"(b1a),
                      "+v"(w1xb), "+v"(w1yb), "+v"(b1b),
                      "+v"(b2j), "+v"(w3j4), "+v"(b3v));

    float y    = 0.0f;
    float xbuf = 0.0f;   // per wave: lane l holds x[(tblk+l)*B + b]
    float ybuf = 0.0f;   // wave 0: lane l holds y_{tblk+l+1}
    if (tid == 0) out[b] = 0.0f;        // y_0 = 0

    const float4* h4 = (const float4*)&h1buf[w][s * 36];

    for (int t = 0; t < T_STEPS - 1; ++t) {
        const int tm = t & 63;
        if (tm == 0)                                // one x block per 64 steps
            xbuf = x[(t + lane) * BATCH + b];
        float xv = bcast_lane(xbuf, tm);            // uniform (SGPR)

        // ---- layer 1: lane computes h1[lane] and h1[lane+64] -> own wave's
        // padded region. Same-wave RAW -> lgkmcnt only, NO barrier.
        float ha = fast_tanh(fmaf(y, w1ya, fmaf(xv, w1xa, b1a)));
        float hb = fast_tanh(fmaf(y, w1yb, fmaf(xv, w1xb, b1b)));
        h1buf[w][((lane >> 5)    ) * 36 + (lane & 31)] = ha;
        h1buf[w][((lane >> 5) + 2) * 36 + (lane & 31)] = hb;

        // ---- layer 2: 8 b128 reads of own chunk + 16 v_pk_fma_f32 ----
        v2f a0 = {0.f, 0.f}, a1 = {0.f, 0.f}, a2 = {0.f, 0.f}, a3 = {0.f, 0.f};
        {
            float4 q0 = h4[0], q1 = h4[1], q2 = h4[2], q3 = h4[3];
            float4 q4 = h4[4], q5 = h4[5], q6 = h4[6], q7 = h4[7];
            v2f h0 = {q0.x, q0.y}, h1_ = {q0.z, q0.w};
            v2f h2 = {q1.x, q1.y}, h3 = {q1.z, q1.w};
            v2f h4v = {q2.x, q2.y}, h5 = {q2.z, q2.w};
            v2f h6 = {q3.x, q3.y}, h7 = {q3.z, q3.w};
            v2f h8 = {q4.x, q4.y}, h9 = {q4.z, q4.w};
            v2f hA = {q5.x, q5.y}, hB = {q5.z, q5.w};
            v2f hC = {q6.x, q6.y}, hD = {q6.z, q6.w};
            v2f hE = {q7.x, q7.y}, hF = {q7.z, q7.w};
            a0 += wp0 * h0;  a1 += wp1 * h1_; a2 += wp2 * h2;  a3 += wp3 * h3;
            a0 += wp4 * h4v; a1 += wp5 * h5;  a2 += wp6 * h6;  a3 += wp7 * h7;
            a0 += wp8 * h8;  a1 += wp9 * h9;  a2 += wp10 * hA; a3 += wp11 * hB;
            a0 += wp12 * hC; a1 += wp13 * hD; a2 += wp14 * hE; a3 += wp15 * hF;
        }
        v2f ap = (a0 + a1) + (a2 + a3);

        // ---- k-partials combine IN-QUAD (2 DPP adds, no LDS, no barrier) ----
        float z2 = quad_sum(ap.x + ap.y);           // full dot for unit j

        // ---- layer 2 tanh + layer 3 + in-wave reduce ----
        float h2 = fast_tanh(z2 + b2j);
        float dyw = wave64_sum(w3j4 * h2);          // this wave's 16 units

        // ---- cross-wave exchange: ONE scalar per wave ----
        if (lane == 0) dyx[t & 1][w] = dyw;
        __syncthreads();                            // the ONLY barrier
        const float4* dx4 = (const float4*)dyx[t & 1];
        float4 r0 = dx4[0], r1 = dx4[1];            // broadcast reads
        y += ((r0.x + r0.y) + (r0.z + r0.w))
           + ((r1.x + r1.y) + (r1.z + r1.w)) + b3v; // DT = 1.0

        // capture + batched store (wave 0 only; wave-uniform branch)
        if (tid < 64) {
            ybuf = (lane == tm) ? y : ybuf;
            if (tm == 63)
                out[(t - 62 + lane) * BATCH + b] = ybuf;
        }
    }
    // tail: t=8128..8190 captured y_8129..y_8191 in lanes 0..62 of wave 0
    if (tid < 63)
        out[(T_STEPS - 63 + lane) * BATCH + b] = ybuf;
}

extern "C" void kernel_launch(void* const* d_in, const int* in_sizes, int n_in,
                              void* d_out, int out_size, void* d_ws, size_t ws_size,
                              hipStream_t stream) {
    const float* x  = (const float*)d_in[0];
    const float* W1 = (const float*)d_in[1];
    const float* b1 = (const float*)d_in[2];
    const float* W2 = (const float*)d_in[3];
    const float* b2 = (const float*)d_in[4];
    const float* W3 = (const float*)d_in[5];
    const float* b3 = (const float*)d_in[6];

    odenet_scan<<<dim3(BATCH), dim3(NTHR), 0, stream>>>(
        x, W1, b1, W2, b2, W3, b3, (float*)d_out);
}

// Round 15
// 4014.953 us; speedup vs baseline: 2.2293x; 1.0016x over previous
//
#include <hip/hip_runtime.h>

#define T_STEPS 8192
#define BATCH   128
#define HID     128
#define NTHR    512               // 8 waves, 2/SIMD, 1 block/CU

typedef float v2f __attribute__((ext_vector_type(2)));

// tanh(z) = 1 - 2/(1+e^{2z}) -- 5 instrs, NaN-free at both infinities.
__device__ __forceinline__ float fast_tanh(float z) {
    float e = __expf(2.0f * z);
    float r = __builtin_amdgcn_rcpf(1.0f + e);
    return fmaf(-2.0f, r, 1.0f);
}

// sum over the 4 lanes of a quad via 2 quad_perm DPP adds (all lanes get it).
__device__ __forceinline__ float quad_sum(float x) {
    int t1 = __builtin_amdgcn_update_dpp(0, __builtin_bit_cast(int, x),
                                         0xB1 /*[1,0,3,2]*/, 0xf, 0xf, false);
    x += __builtin_bit_cast(float, t1);
    int t2 = __builtin_amdgcn_update_dpp(0, __builtin_bit_cast(int, x),
                                         0x4E /*[2,3,0,1]*/, 0xf, 0xf, false);
    x += __builtin_bit_cast(float, t2);
    return x;
}

// wave sum of QUAD-UNIFORM values: row_shr1/2 are redundant -> 4 DPP adds
// (shr4, shr8, bcast15, bcast31), result from lane 63. ~16 cyc shorter chain.
__device__ __forceinline__ float wave_sum_quaduniform(float x) {
#define DPP_ADD(ctrl) do {                                                        \
        int t_ = __builtin_amdgcn_update_dpp(0, __builtin_bit_cast(int, x),       \
                                             (ctrl), 0xf, 0xf, false);            \
        x += __builtin_bit_cast(float, t_); } while (0)
    DPP_ADD(0x114);  // row_shr:4
    DPP_ADD(0x118);  // row_shr:8   -> lanes 12-15 of each row16 hold row sum
    DPP_ADD(0x142);  // row_bcast:15
    DPP_ADD(0x143);  // row_bcast:31 -> lane 63 holds wave total
#undef DPP_ADD
    int s_ = __builtin_amdgcn_readlane(__builtin_bit_cast(int, x), 63);
    return __builtin_bit_cast(float, s_);
}

__device__ __forceinline__ float bcast_lane(float v, int l) {
    int r = __builtin_amdgcn_readlane(__builtin_bit_cast(int, v), l);
    return __builtin_bit_cast(float, r);
}

#define FORALL16(M) M(0) M(1) M(2) M(3) M(4) M(5) M(6) M(7) \
                    M(8) M(9) M(10) M(11) M(12) M(13) M(14) M(15)

// R15 = R14 (quad-local k-split, one barrier, scalar exchange) with the
// dependent-op chain shaved: lgkm-only barrier (no vmcnt drain), 4-DPP wave
// reduce, x-side of layer1 precomputed pre-barrier, x prefetched one block
// ahead, symmetric per-wave capture (equal barrier arrival).
__global__ __launch_bounds__(NTHR, 2) void odenet_scan(
    const float* __restrict__ x,
    const float* __restrict__ W1, const float* __restrict__ b1,
    const float* __restrict__ W2, const float* __restrict__ b2,
    const float* __restrict__ W3, const float* __restrict__ b3,
    float* __restrict__ out) {

    const int b    = blockIdx.x;        // batch element
    const int tid  = threadIdx.x;
    const int w    = tid >> 6;          // wave 0..7
    const int lane = tid & 63;
    const int j    = (w << 4) | (lane >> 2);   // owned output unit
    const int s    = lane & 3;                 // k-chunk [32s, 32s+32)

    // wave-private h1: 4 chunks x 36 floats (32 + 4 pad) -> disjoint bank quads
    __shared__ __align__(16) float h1buf[8][144];
    __shared__ __align__(16) float dyx[2][8];  // [parity][wave] dy partials

    // ---- W2 fragment: rows [32s, 32s+32) of column j, packed as 16 v2f ----
    const float* col = W2 + j;          // column j, row stride HID
    const int kb = s << 5;
#define DECLW(i) v2f wp##i = {col[(kb + 2*(i) + 0) * HID],                        \
                              col[(kb + 2*(i) + 1) * HID]};
    FORALL16(DECLW)
#undef DECLW
#define PINW(i) asm volatile("" : "+v"(wp##i));
    FORALL16(PINW)
#undef PINW

    // layer-1 weights for the two h1 units this lane computes (k=lane, lane+64)
    float w1xa = W1[lane],      w1ya = W1[HID + lane],      b1a = b1[lane];
    float w1xb = W1[lane + 64], w1yb = W1[HID + lane + 64], b1b = b1[lane + 64];
    float b2j = b2[j], w3j = W3[j], b3v = b3[0];
    asm volatile("" : "+v"(w1xa), "+v"(w1ya), "+v"(b1a),
                      "+v"(w1xb), "+v"(w1yb), "+v"(b1b),
                      "+v"(b2j), "+v"(w3j), "+v"(b3v));

    float y    = 0.0f;
    float ybuf = 0.0f;                  // ALL waves capture (symmetric arrival)
    if (w == 0 && lane == 0) out[b] = 0.0f;   // y_0 = 0

    // ---- x double-buffer: xbuf = current 64-step block, xnext = next ----
    float xbuf  = x[lane * BATCH + b];                 // block 0
    int   nb    = 64;                                  // next block base
    float xnext = x[min(nb + lane, T_STEPS - 1) * BATCH + b];
    // x-side of layer 1 for t = 0 (y-independent)
    float xv = bcast_lane(xbuf, 0);
    float ax = fmaf(xv, w1xa, b1a);
    float bx = fmaf(xv, w1xb, b1b);

    const float4* h4 = (const float4*)&h1buf[w][s * 36];

    for (int t = 0; t < T_STEPS - 1; ++t) {
        const int tm = t & 63;

        // ---- layer 1 (critical path from y: fma+tanh+write only) ----
        float ha = fast_tanh(fmaf(y, w1ya, ax));
        float hb = fast_tanh(fmaf(y, w1yb, bx));
        h1buf[w][((lane >> 5)    ) * 36 + (lane & 31)] = ha;
        h1buf[w][((lane >> 5) + 2) * 36 + (lane & 31)] = hb;

        // ---- layer 2: 8 b128 reads of own chunk + 16 v_pk_fma_f32 ----
        v2f a0 = {0.f, 0.f}, a1 = {0.f, 0.f}, a2 = {0.f, 0.f}, a3 = {0.f, 0.f};
        {
            float4 q0 = h4[0], q1 = h4[1], q2 = h4[2], q3 = h4[3];
            float4 q4 = h4[4], q5 = h4[5], q6 = h4[6], q7 = h4[7];
            v2f h0 = {q0.x, q0.y}, h1_ = {q0.z, q0.w};
            v2f h2 = {q1.x, q1.y}, h3 = {q1.z, q1.w};
            v2f h4v = {q2.x, q2.y}, h5 = {q2.z, q2.w};
            v2f h6 = {q3.x, q3.y}, h7 = {q3.z, q3.w};
            v2f h8 = {q4.x, q4.y}, h9 = {q4.z, q4.w};
            v2f hA = {q5.x, q5.y}, hB = {q5.z, q5.w};
            v2f hC = {q6.x, q6.y}, hD = {q6.z, q6.w};
            v2f hE = {q7.x, q7.y}, hF = {q7.z, q7.w};
            a0 += wp0 * h0;  a1 += wp1 * h1_; a2 += wp2 * h2;  a3 += wp3 * h3;
            a0 += wp4 * h4v; a1 += wp5 * h5;  a2 += wp6 * h6;  a3 += wp7 * h7;
            a0 += wp8 * h8;  a1 += wp9 * h9;  a2 += wp10 * hA; a3 += wp11 * hB;
            a0 += wp12 * hC; a1 += wp13 * hD; a2 += wp14 * hE; a3 += wp15 * hF;
        }
        v2f ap = (a0 + a1) + (a2 + a3);

        // ---- combine k-partials in-quad, tanh, layer-3, 4-DPP wave reduce ----
        float z2  = quad_sum(ap.x + ap.y);
        float h2  = fast_tanh(z2 + b2j);
        float dyw = wave_sum_quaduniform(w3j * h2);  // this wave's 16 units

        if (lane == 0) dyx[t & 1][w] = dyw;

        // ---- next step's x-side prep (y-independent; fills barrier wait) ----
        const int tmn = (t + 1) & 63;
        if (tmn == 0) {                              // rotate x blocks
            xbuf = xnext;
            nb += 64;
            xnext = x[min(nb + lane, T_STEPS - 1) * BATCH + b];
        }
        float xvn = bcast_lane(xbuf, tmn);
        float axn = fmaf(xvn, w1xa, b1a);
        float bxn = fmaf(xvn, w1xb, b1b);

        // ---- lgkm-only barrier: out-stores/x-loads stay in flight ----
        asm volatile("s_waitcnt lgkmcnt(0)\n\ts_barrier" ::: "memory");

        const float4* dx4 = (const float4*)dyx[t & 1];
        float4 r0 = dx4[0], r1 = dx4[1];             // broadcast reads
        y += ((r0.x + r0.y) + (r0.z + r0.w))
           + ((r1.x + r1.y) + (r1.z + r1.w)) + b3v;  // DT = 1.0

        ybuf = (lane == tm) ? y : ybuf;              // all waves (symmetric)
        if (w == 0 && tm == 63)
            out[(t - 62 + lane) * BATCH + b] = ybuf;

        ax = axn; bx = bxn;
    }
    // tail: t=8128..8190 captured y_8129..y_8191 in lanes 0..62
    if (w == 0 && lane < 63)
        out[(T_STEPS - 63 + lane) * BATCH + b] = ybuf;
}

extern "C" void kernel_launch(void* const* d_in, const int* in_sizes, int n_in,
                              void* d_out, int out_size, void* d_ws, size_t ws_size,
                              hipStream_t stream) {
    const float* x  = (const float*)d_in[0];
    const float* W1 = (const float*)d_in[1];
    const float* b1 = (const float*)d_in[2];
    const float* W2 = (const float*)d_in[3];
    const float* b2 = (const float*)d_in[4];
    const float* W3 = (const float*)d_in[5];
    const float* b3 = (const float*)d_in[6];

    odenet_scan<<<dim3(BATCH), dim3(NTHR), 0, stream>>>(
        x, W1, b1, W2, b2, W3, b3, (float*)d_out);
}

// Round 16
// 4009.809 us; speedup vs baseline: 2.2321x; 1.0013x over previous
//
#include <hip/hip_runtime.h>

#define T_STEPS 8192
#define BATCH   128
#define HID     128
#define NTHR    256               // 4 waves, 1/SIMD: no issue-port sharing

typedef float v2f __attribute__((ext_vector_type(2)));

// tanh(z) = 1 - 2/(1+e^{2z}) -- 5 instrs, NaN-free at both infinities.
__device__ __forceinline__ float fast_tanh(float z) {
    float e = __expf(2.0f * z);
    float r = __builtin_amdgcn_rcpf(1.0f + e);
    return fmaf(-2.0f, r, 1.0f);
}

// sum the 2 lanes of a pair (xor1 within quad); both lanes get the result.
__device__ __forceinline__ float pair_sum(float x) {
    int t1 = __builtin_amdgcn_update_dpp(0, __builtin_bit_cast(int, x),
                                         0xB1 /*quad_perm [1,0,3,2]*/,
                                         0xf, 0xf, false);
    return x + __builtin_bit_cast(float, t1);
}

// wave sum of PAIR-UNIFORM values -> total lands in lane 63 (5 DPP adds,
// no readlane: the consumer is a lane-63-predicated ds_write).
__device__ __forceinline__ float wave_sum_pairuniform_l63(float x) {
#define DPP_ADD(ctrl) do {                                                        \
        int t_ = __builtin_amdgcn_update_dpp(0, __builtin_bit_cast(int, x),       \
                                             (ctrl), 0xf, 0xf, false);            \
        x += __builtin_bit_cast(float, t_); } while (0)
    DPP_ADD(0x112);  // row_shr:2
    DPP_ADD(0x114);  // row_shr:4
    DPP_ADD(0x118);  // row_shr:8   -> row sums at row tails
    DPP_ADD(0x142);  // row_bcast:15
    DPP_ADD(0x143);  // row_bcast:31 -> lane 63 holds wave total
#undef DPP_ADD
    return x;
}

__device__ __forceinline__ float bcast_lane(float v, int l) {
    int r = __builtin_amdgcn_readlane(__builtin_bit_cast(int, v), l);
    return __builtin_bit_cast(float, r);
}

#define FORALL32(M) M(0) M(1) M(2) M(3) M(4) M(5) M(6) M(7) \
                    M(8) M(9) M(10) M(11) M(12) M(13) M(14) M(15) \
                    M(16) M(17) M(18) M(19) M(20) M(21) M(22) M(23) \
                    M(24) M(25) M(26) M(27) M(28) M(29) M(30) M(31)

// R16: R15's lean skeleton at 4 waves / 1 per SIMD. R15 post-mortem: ~240 of
// the ~890 real cyc/step is issue-port sharing between 2 lockstep waves on
// each SIMD (correlated stalls hide nothing; contention costs plenty). Here:
// lane pair = (j, s): j=(w<<5)|(lane>>1), s=lane&1, 64 weights/lane (32 v2f,
// ~110 VGPR < 256 cap). Pair combine = 1 DPP; wave reduce = 5 DPP to lane 63
// (write direct, no readlane); exchange = 4 floats = ONE b128 read; barrier
// spans 4 waves.
__global__ __launch_bounds__(NTHR, 2) void odenet_scan(
    const float* __restrict__ x,
    const float* __restrict__ W1, const float* __restrict__ b1,
    const float* __restrict__ W2, const float* __restrict__ b2,
    const float* __restrict__ W3, const float* __restrict__ b3,
    float* __restrict__ out) {

    const int b    = blockIdx.x;        // batch element
    const int tid  = threadIdx.x;
    const int w    = tid >> 6;          // wave 0..3
    const int lane = tid & 63;
    const int j    = (w << 5) | (lane >> 1);   // owned output unit
    const int s    = lane & 1;                 // k-chunk [64s, 64s+64)

    // wave-private h1: 2 chunks x 68 floats (64 + 4 pad; 68 = 17 float4 so
    // chunk 1 stays 16B-aligned and bank-shifted by 4)
    __shared__ __align__(16) float h1buf[4][136];
    __shared__ __align__(16) float dyx[2][4];  // [parity][wave] dy partials

    // ---- W2 fragment: rows [64s, 64s+64) of column j, packed as 32 v2f ----
    const float* col = W2 + j;          // column j, row stride HID
    const int kb = s << 6;
#define DECLW(i) v2f wp##i = {col[(kb + 2*(i) + 0) * HID],                        \
                              col[(kb + 2*(i) + 1) * HID]};
    FORALL32(DECLW)
#undef DECLW
#define PINW(i) asm volatile("" : "+v"(wp##i));
    FORALL32(PINW)
#undef PINW

    // layer-1 weights for the two h1 units this lane computes (k=lane, lane+64)
    float w1xa = W1[lane],      w1ya = W1[HID + lane],      b1a = b1[lane];
    float w1xb = W1[lane + 64], w1yb = W1[HID + lane + 64], b1b = b1[lane + 64];
    float b2j = b2[j], w3j = W3[j], b3v = b3[0];
    asm volatile("" : "+v"(w1xa), "+v"(w1ya), "+v"(b1a),
                      "+v"(w1xb), "+v"(w1yb), "+v"(b1b),
                      "+v"(b2j), "+v"(w3j), "+v"(b3v));

    float y    = 0.0f;
    float ybuf = 0.0f;                  // all waves capture (symmetric arrival)
    if (w == 0 && lane == 0) out[b] = 0.0f;   // y_0 = 0

    // ---- x double-buffer: xbuf = current 64-step block, xnext = next ----
    float xbuf  = x[lane * BATCH + b];                 // block 0
    int   nb    = 64;                                  // next block base
    float xnext = x[min(nb + lane, T_STEPS - 1) * BATCH + b];
    float xv = bcast_lane(xbuf, 0);
    float ax = fmaf(xv, w1xa, b1a);     // x-side of layer 1 for t=0
    float bx = fmaf(xv, w1xb, b1b);

    const float4* h4 = (const float4*)&h1buf[w][s * 68];

    for (int t = 0; t < T_STEPS - 1; ++t) {
        const int tm = t & 63;

        // ---- layer 1 (critical path from y: fma+tanh+write only) ----
        float ha = fast_tanh(fmaf(y, w1ya, ax));
        float hb = fast_tanh(fmaf(y, w1yb, bx));
        h1buf[w][lane]      = ha;       // chunk 0, 2-way bank alias (free)
        h1buf[w][68 + lane] = hb;       // chunk 1

        // ---- layer 2: 16 b128 reads of own chunk + 32 v_pk_fma_f32 ----
        v2f a0 = {0.f, 0.f}, a1 = {0.f, 0.f}, a2 = {0.f, 0.f}, a3 = {0.f, 0.f};
        {
            float4 q;
#define FMAP(qi, WA, WB, AA, AB) q = h4[qi];                                      \
            { v2f lo = {q.x, q.y}, hi = {q.z, q.w};                               \
              AA += WA * lo; AB += WB * hi; }
            FMAP( 0, wp0 , wp1 , a0, a1) FMAP( 1, wp2 , wp3 , a2, a3)
            FMAP( 2, wp4 , wp5 , a0, a1) FMAP( 3, wp6 , wp7 , a2, a3)
            FMAP( 4, wp8 , wp9 , a0, a1) FMAP( 5, wp10, wp11, a2, a3)
            FMAP( 6, wp12, wp13, a0, a1) FMAP( 7, wp14, wp15, a2, a3)
            FMAP( 8, wp16, wp17, a0, a1) FMAP( 9, wp18, wp19, a2, a3)
            FMAP(10, wp20, wp21, a0, a1) FMAP(11, wp22, wp23, a2, a3)
            FMAP(12, wp24, wp25, a0, a1) FMAP(13, wp26, wp27, a2, a3)
            FMAP(14, wp28, wp29, a0, a1) FMAP(15, wp30, wp31, a2, a3)
#undef FMAP
        }
        v2f ap = (a0 + a1) + (a2 + a3);

        // ---- combine k-halves in-pair (1 DPP), tanh, layer-3, wave reduce ----
        float z2  = pair_sum(ap.x + ap.y);           // full dot for unit j
        float h2  = fast_tanh(z2 + b2j);
        float dyw = wave_sum_pairuniform_l63(w3j * h2);
        if (lane == 63) dyx[t & 1][w] = dyw;         // direct from lane 63

        // ---- next step's x-side prep (y-independent; fills barrier wait) ----
        const int tmn = (t + 1) & 63;
        if (tmn == 0) {                              // rotate x blocks
            xbuf = xnext;
            nb += 64;
            xnext = x[min(nb + lane, T_STEPS - 1) * BATCH + b];
        }
        float xvn = bcast_lane(xbuf, tmn);
        float axn = fmaf(xvn, w1xa, b1a);
        float bxn = fmaf(xvn, w1xb, b1b);

        // ---- lgkm-only barrier (4 waves): stores/x-loads stay in flight ----
        asm volatile("s_waitcnt lgkmcnt(0)\n\ts_barrier" ::: "memory");

        float4 d = *(const float4*)&dyx[t & 1][0];   // one broadcast b128
        y += ((d.x + d.y) + (d.z + d.w)) + b3v;      // DT = 1.0

        ybuf = (lane == tm) ? y : ybuf;              // all waves (symmetric)
        if (w == 0 && tm == 63)
            out[(t - 62 + lane) * BATCH + b] = ybuf;

        ax = axn; bx = bxn;
    }
    // tail: t=8128..8190 captured y_8129..y_8191 in lanes 0..62
    if (w == 0 && lane < 63)
        out[(T_STEPS - 63 + lane) * BATCH + b] = ybuf;
}

extern "C" void kernel_launch(void* const* d_in, const int* in_sizes, int n_in,
                              void* d_out, int out_size, void* d_ws, size_t ws_size,
                              hipStream_t stream) {
    const float* x  = (const float*)d_in[0];
    const float* W1 = (const float*)d_in[1];
    const float* b1 = (const float*)d_in[2];
    const float* W2 = (const float*)d_in[3];
    const float* b2 = (const float*)d_in[4];
    const float* W3 = (const float*)d_in[5];
    const float* b3 = (const float*)d_in[6];

    odenet_scan<<<dim3(BATCH), dim3(NTHR), 0, stream>>>(
        x, W1, b1, W2, b2, W3, b3, (float*)d_out);
}